// Round 1
// 1058.943 us; speedup vs baseline: 1.0184x; 1.0184x over previous
//
#include <hip/hip_runtime.h>

// Dims (fixed for this problem instance; start_pos read from device)
#define BATCH 32
#define DMODEL 4096
#define NH 32
#define NKV 8
#define DH 128
#define TCACHE 4096
#define NCOLS_QKV 6144   // 4096 q + 1024 k + 1024 v

// ---------------------------------------------------------------------------
// Kernel 1: QKV projection, split-K partials.
// grid (24, nchunk), block 256. Each block: 256 cols x 32 batches x dchunk K.
// Thread (tx,ty): cols col4..col4+3 (float4), batches ty*8..ty*8+7.
// ---------------------------------------------------------------------------
__global__ __launch_bounds__(256) void qkv_partial(
    const float* __restrict__ x, const float* __restrict__ wq,
    const float* __restrict__ wk, const float* __restrict__ wv,
    float* __restrict__ pbuf, int dchunk) {
  __shared__ float xs[BATCH * 128];
  const int tid = threadIdx.x, tx = tid & 63, ty = tid >> 6;
  const int bx = blockIdx.x, by = blockIdx.y;

  const float* W;
  int ldw, colw, colp;
  if (bx < 16)      { W = wq; ldw = 4096; colw = bx * 256 + tx * 4;        colp = colw; }
  else if (bx < 20) { W = wk; ldw = 1024; colw = (bx - 16) * 256 + tx * 4; colp = 4096 + colw; }
  else              { W = wv; ldw = 1024; colw = (bx - 20) * 256 + tx * 4; colp = 5120 + colw; }

  float4 acc[8];
#pragma unroll
  for (int i = 0; i < 8; ++i) acc[i] = make_float4(0.f, 0.f, 0.f, 0.f);

  const int d0 = by * dchunk;
  for (int s = 0; s < dchunk; s += 128) {
    __syncthreads();
    for (int i = tid; i < BATCH * 128; i += 256)
      xs[i] = x[(size_t)(i >> 7) * DMODEL + d0 + s + (i & 127)];
    __syncthreads();

    const float* wrow = W + (size_t)(d0 + s) * ldw + colw;
#pragma unroll 4
    for (int dd = 0; dd < 128; ++dd) {
      float4 w4 = *(const float4*)wrow;
      wrow += ldw;
#pragma unroll
      for (int i = 0; i < 8; ++i) {
        float xv = xs[(ty * 8 + i) * 128 + dd];
        acc[i].x += xv * w4.x; acc[i].y += xv * w4.y;
        acc[i].z += xv * w4.z; acc[i].w += xv * w4.w;
      }
    }
  }
#pragma unroll
  for (int i = 0; i < 8; ++i) {
    int b = ty * 8 + i;
    *(float4*)&pbuf[((size_t)by * BATCH + b) * NCOLS_QKV + colp] = acc[i];
  }
}

// ---------------------------------------------------------------------------
// Kernel 2: sum split-K partials + apply rotation.
// grid (48, 32): x = slot (0..31 q-head, 32..39 k-head, 40..47 v-head), y = b.
// block 128 (one thread per output element e).
// ---------------------------------------------------------------------------
__global__ __launch_bounds__(128) void rot_combine(
    const float* __restrict__ pbuf, const float* __restrict__ rot,
    float* __restrict__ q_ws, float* __restrict__ k_ws, float* __restrict__ v_ws,
    int nc) {
  __shared__ float xvec[DH];
  const int slot = blockIdx.x, b = blockIdx.y, e = threadIdx.x;

  int colbase;
  if (slot < 32)      colbase = slot * DH;
  else if (slot < 40) colbase = 4096 + (slot - 32) * DH;
  else                colbase = 5120 + (slot - 40) * DH;

  float s = 0.f;
  for (int c = 0; c < nc; ++c)
    s += pbuf[((size_t)c * BATCH + b) * NCOLS_QKV + colbase + e];

  if (slot >= 40) {  // v: no rotation
    v_ws[(b * NKV + slot - 40) * DH + e] = s;
    return;
  }
  xvec[e] = s;
  __syncthreads();

  const float* rb = rot + (size_t)b * DH * DH + e;
  float o = 0.f;
#pragma unroll 8
  for (int d = 0; d < DH; ++d) o += xvec[d] * rb[(size_t)d * DH];

  if (slot < 32) q_ws[(b * NH + slot) * DH + e] = o;
  else           k_ws[(b * NKV + slot - 32) * DH + e] = o;
}

// ---------------------------------------------------------------------------
// Kernel 3: attention decode. grid (NKV, BATCH), block 1024 (16 waves).
// 16 waves/CU = 4 waves/SIMD for latency hiding (was 4 waves/CU = 1/SIMD).
// Phase 1: scores (4 q-heads share one K stream) -> LDS, fused running max.
// Softmax exp+sum. Phase 2: PV, 16 waves own contiguous t-chunks.
// ---------------------------------------------------------------------------
__device__ __forceinline__ void dot128(const float* __restrict__ krp,
                                       const float* __restrict__ qhp,
                                       float& a0, float& a1, float& a2, float& a3) {
  const float4* kr = (const float4*)krp;
  const float4* q4 = (const float4*)qhp;
  a0 = a1 = a2 = a3 = 0.f;
#pragma unroll 8
  for (int c = 0; c < 32; ++c) {
    float4 kk = kr[c];
    float4 qa = q4[c], qb = q4[32 + c], qc = q4[64 + c], qd = q4[96 + c];
    a0 += kk.x * qa.x + kk.y * qa.y + kk.z * qa.z + kk.w * qa.w;
    a1 += kk.x * qb.x + kk.y * qb.y + kk.z * qb.z + kk.w * qb.w;
    a2 += kk.x * qc.x + kk.y * qc.y + kk.z * qc.z + kk.w * qc.w;
    a3 += kk.x * qd.x + kk.y * qd.y + kk.z * qd.z + kk.w * qd.w;
  }
}

__global__ __launch_bounds__(1024) void attn_kernel(
    const float* __restrict__ q_ws, const float* __restrict__ k_ws,
    const float* __restrict__ v_ws, const float* __restrict__ keys,
    const float* __restrict__ values, const float* __restrict__ mask,
    const int* __restrict__ sp_ptr, float* __restrict__ out_ws) {
  __shared__ float sc[4 * TCACHE];   // 64 KB scores/probs
  __shared__ float qh[4 * DH];
  __shared__ float kn[DH], vn[DH];
  __shared__ float red[64];          // 16 waves x 4 heads
  __shared__ float mg[4], il[4];
  __shared__ float op[16 * 4 * DH];  // 32 KB per-wave PV partials

  const int kv = blockIdx.x, b = blockIdx.y, tid = threadIdx.x;
  const int lane = tid & 63, w = tid >> 6;   // w in 0..15
  const int sp = *sp_ptr;

  if (tid < 512)       qh[tid] = q_ws[(size_t)(b * NH + kv * 4) * DH + tid] * 0.08838834764831845f;
  else if (tid < 640)  kn[tid - 512] = k_ws[(b * NKV + kv) * DH + (tid - 512)];
  else if (tid < 768)  vn[tid - 640] = v_ws[(b * NKV + kv) * DH + (tid - 640)];
  __syncthreads();

  const size_t kvbase = (size_t)(b * NKV + kv) << 19;  // * TCACHE * DH
  const size_t mb0 = ((size_t)(kv * 4 + 0) * BATCH + b) << 12;
  const size_t mb1 = ((size_t)(kv * 4 + 1) * BATCH + b) << 12;
  const size_t mb2 = ((size_t)(kv * 4 + 2) * BATCH + b) << 12;
  const size_t mb3 = ((size_t)(kv * 4 + 3) * BATCH + b) << 12;

  // ---- phase 1: scores for t in [0, sp) from cache, fused max tracking ----
  float lm0 = -3.4e38f, lm1 = -3.4e38f, lm2 = -3.4e38f, lm3 = -3.4e38f;
  for (int t = tid; t < sp; t += 1024) {
    float a0, a1, a2, a3;
    dot128(keys + kvbase + ((size_t)t << 7), qh, a0, a1, a2, a3);
    a0 += mask[mb0 + t]; a1 += mask[mb1 + t];
    a2 += mask[mb2 + t]; a3 += mask[mb3 + t];
    sc[t] = a0;              lm0 = fmaxf(lm0, a0);
    sc[TCACHE + t] = a1;     lm1 = fmaxf(lm1, a1);
    sc[2 * TCACHE + t] = a2; lm2 = fmaxf(lm2, a2);
    sc[3 * TCACHE + t] = a3; lm3 = fmaxf(lm3, a3);
  }
  // t == sp uses the freshly projected (rotated) k
  if (tid == (sp & 1023)) {
    float a0, a1, a2, a3;
    dot128(kn, qh, a0, a1, a2, a3);
    a0 += mask[mb0 + sp]; a1 += mask[mb1 + sp];
    a2 += mask[mb2 + sp]; a3 += mask[mb3 + sp];
    sc[sp] = a0;              lm0 = fmaxf(lm0, a0);
    sc[TCACHE + sp] = a1;     lm1 = fmaxf(lm1, a1);
    sc[2 * TCACHE + sp] = a2; lm2 = fmaxf(lm2, a2);
    sc[3 * TCACHE + sp] = a3; lm3 = fmaxf(lm3, a3);
  }

  // ---- softmax: max reduce (wave shuffle -> LDS -> cross-wave) ----
#pragma unroll
  for (int off = 32; off > 0; off >>= 1) {
    lm0 = fmaxf(lm0, __shfl_down(lm0, off, 64));
    lm1 = fmaxf(lm1, __shfl_down(lm1, off, 64));
    lm2 = fmaxf(lm2, __shfl_down(lm2, off, 64));
    lm3 = fmaxf(lm3, __shfl_down(lm3, off, 64));
  }
  if (lane == 0) { red[w * 4] = lm0; red[w * 4 + 1] = lm1; red[w * 4 + 2] = lm2; red[w * 4 + 3] = lm3; }
  __syncthreads();
  if (tid < 4) {
    float m = red[tid];
#pragma unroll
    for (int ww = 1; ww < 16; ++ww) m = fmaxf(m, red[ww * 4 + tid]);
    mg[tid] = m;
  }
  __syncthreads();

  // ---- softmax: exp + sum (probs written back into sc) ----
  const float m0 = mg[0], m1 = mg[1], m2 = mg[2], m3 = mg[3];
  float s0 = 0.f, s1 = 0.f, s2 = 0.f, s3 = 0.f;
  for (int t = tid; t <= sp; t += 1024) {
    float e0 = __expf(sc[t] - m0);              sc[t] = e0;              s0 += e0;
    float e1 = __expf(sc[TCACHE + t] - m1);     sc[TCACHE + t] = e1;     s1 += e1;
    float e2 = __expf(sc[2 * TCACHE + t] - m2); sc[2 * TCACHE + t] = e2; s2 += e2;
    float e3 = __expf(sc[3 * TCACHE + t] - m3); sc[3 * TCACHE + t] = e3; s3 += e3;
  }
#pragma unroll
  for (int off = 32; off > 0; off >>= 1) {
    s0 += __shfl_down(s0, off, 64);
    s1 += __shfl_down(s1, off, 64);
    s2 += __shfl_down(s2, off, 64);
    s3 += __shfl_down(s3, off, 64);
  }
  if (lane == 0) { red[w * 4] = s0; red[w * 4 + 1] = s1; red[w * 4 + 2] = s2; red[w * 4 + 3] = s3; }
  __syncthreads();
  if (tid < 4) {
    float s = 0.f;
#pragma unroll
    for (int ww = 0; ww < 16; ++ww) s += red[ww * 4 + tid];
    il[tid] = 1.0f / s;
  }
  __syncthreads();

  // ---- phase 2: PV. Each wave owns a contiguous t-chunk; coalesced V rows ----
  const int d2 = lane * 2;
  const int cnt = (sp + 16) >> 4;          // ceil((sp+1)/16)
  const int t0 = w * cnt;
  int t1 = t0 + cnt; if (t1 > sp + 1) t1 = sp + 1;
  const int tg = (t1 < sp) ? t1 : sp;      // global part: [t0, tg)

  float ox0 = 0.f, oy0 = 0.f, ox1 = 0.f, oy1 = 0.f;
  float ox2 = 0.f, oy2 = 0.f, ox3 = 0.f, oy3 = 0.f;
#pragma unroll 4
  for (int t = t0; t < tg; ++t) {
    float2 vv = *(const float2*)(values + kvbase + ((size_t)t << 7) + d2);
    float p0 = sc[t], p1 = sc[TCACHE + t], p2 = sc[2 * TCACHE + t], p3 = sc[3 * TCACHE + t];
    ox0 += p0 * vv.x; oy0 += p0 * vv.y;
    ox1 += p1 * vv.x; oy1 += p1 * vv.y;
    ox2 += p2 * vv.x; oy2 += p2 * vv.y;
    ox3 += p3 * vv.x; oy3 += p3 * vv.y;
  }
  if (sp >= t0 && sp < t1) {               // new-token row from LDS
    float vx = vn[d2], vy = vn[d2 + 1];
    float p0 = sc[sp], p1 = sc[TCACHE + sp], p2 = sc[2 * TCACHE + sp], p3 = sc[3 * TCACHE + sp];
    ox0 += p0 * vx; oy0 += p0 * vy;
    ox1 += p1 * vx; oy1 += p1 * vy;
    ox2 += p2 * vx; oy2 += p2 * vy;
    ox3 += p3 * vx; oy3 += p3 * vy;
  }
  *(float2*)&op[(w * 4 + 0) * DH + d2] = make_float2(ox0, oy0);
  *(float2*)&op[(w * 4 + 1) * DH + d2] = make_float2(ox1, oy1);
  *(float2*)&op[(w * 4 + 2) * DH + d2] = make_float2(ox2, oy2);
  *(float2*)&op[(w * 4 + 3) * DH + d2] = make_float2(ox3, oy3);
  __syncthreads();

  // cross-wave reduce; thread -> (g = tid>>7, d = tid&127)
  if (tid < 512) {
    const int g = tid >> 7, d = tid & 127;
    float r = 0.f;
#pragma unroll
    for (int ww = 0; ww < 16; ++ww) r += op[(ww * 4 + g) * DH + d];
    out_ws[(size_t)(b * NH + kv * 4 + g) * DH + d] = r * il[g];
  }
}

// ---------------------------------------------------------------------------
// Kernel 4: output projection (out_ws[32][4096] @ wo[4096][4096]), split-K.
// grid (16, nchunk), block 256.
// ---------------------------------------------------------------------------
__global__ __launch_bounds__(256) void out_partial(
    const float* __restrict__ xin, const float* __restrict__ wo,
    float* __restrict__ pbuf, int dchunk) {
  __shared__ float xs[BATCH * 128];
  const int tid = threadIdx.x, tx = tid & 63, ty = tid >> 6;
  const int bx = blockIdx.x, by = blockIdx.y;
  const int col = bx * 256 + tx * 4;

  float4 acc[8];
#pragma unroll
  for (int i = 0; i < 8; ++i) acc[i] = make_float4(0.f, 0.f, 0.f, 0.f);

  const int d0 = by * dchunk;
  for (int s = 0; s < dchunk; s += 128) {
    __syncthreads();
    for (int i = tid; i < BATCH * 128; i += 256)
      xs[i] = xin[(size_t)(i >> 7) * DMODEL + d0 + s + (i & 127)];
    __syncthreads();

    const float* wrow = wo + (size_t)(d0 + s) * DMODEL + col;
#pragma unroll 4
    for (int dd = 0; dd < 128; ++dd) {
      float4 w4 = *(const float4*)wrow;
      wrow += DMODEL;
#pragma unroll
      for (int i = 0; i < 8; ++i) {
        float xv = xs[(ty * 8 + i) * 128 + dd];
        acc[i].x += xv * w4.x; acc[i].y += xv * w4.y;
        acc[i].z += xv * w4.z; acc[i].w += xv * w4.w;
      }
    }
  }
#pragma unroll
  for (int i = 0; i < 8; ++i) {
    int b = ty * 8 + i;
    *(float4*)&pbuf[((size_t)by * BATCH + b) * DMODEL + col] = acc[i];
  }
}

// ---------------------------------------------------------------------------
// Kernel 5: reduce split-K partials into d_out.
// ---------------------------------------------------------------------------
__global__ __launch_bounds__(256) void reduce_out(
    const float* __restrict__ pbuf, float* __restrict__ out, int nc) {
  const int i = blockIdx.x * 256 + threadIdx.x;  // 131072 outputs
  const int b = i >> 12, e = i & 4095;
  float s = 0.f;
  for (int c = 0; c < nc; ++c)
    s += pbuf[((size_t)c * BATCH + b) * DMODEL + e];
  out[i] = s;
}

// ---------------------------------------------------------------------------
extern "C" void kernel_launch(void* const* d_in, const int* in_sizes, int n_in,
                              void* d_out, int out_size, void* d_ws, size_t ws_size,
                              hipStream_t stream) {
  const float* x      = (const float*)d_in[0];
  const float* wq     = (const float*)d_in[1];
  const float* wk     = (const float*)d_in[2];
  const float* wv     = (const float*)d_in[3];
  const float* wo     = (const float*)d_in[4];
  const float* rot    = (const float*)d_in[5];
  const float* mask   = (const float*)d_in[6];
  const float* keys   = (const float*)d_in[7];
  const float* values = (const float*)d_in[8];
  const int*   sp     = (const int*)d_in[9];
  float* out = (float*)d_out;
  float* ws  = (float*)d_ws;

  // aux buffers: q (131072) + k (32768) + v (32768) + attn out (131072)
  const size_t AUXF = 131072 + 32768 + 32768 + 131072;
  size_t wsf = ws_size / sizeof(float);

  int cA = 32;
  while (cA > 1 && (size_t)cA * (BATCH * NCOLS_QKV) + AUXF > wsf) cA >>= 1;
  int cD = 32;
  while (cD > 1 && (size_t)cD * (BATCH * DMODEL) + AUXF > wsf) cD >>= 1;

  size_t pmax = (size_t)cA * (BATCH * NCOLS_QKV);
  if ((size_t)cD * (BATCH * DMODEL) > pmax) pmax = (size_t)cD * (BATCH * DMODEL);

  float* pbuf   = ws;
  float* q_ws   = ws + pmax;
  float* k_ws   = q_ws + 131072;
  float* v_ws   = k_ws + 32768;
  float* out_ws = v_ws + 32768;

  qkv_partial<<<dim3(24, cA), 256, 0, stream>>>(x, wq, wk, wv, pbuf, DMODEL / cA);
  rot_combine<<<dim3(48, BATCH), 128, 0, stream>>>(pbuf, rot, q_ws, k_ws, v_ws, cA);
  attn_kernel<<<dim3(NKV, BATCH), 1024, 0, stream>>>(q_ws, k_ws, v_ws, keys, values, mask, sp, out_ws);
  out_partial<<<dim3(16, cD), 256, 0, stream>>>(out_ws, wo, pbuf, DMODEL / cD);
  reduce_out<<<dim3(512), 256, 0, stream>>>(pbuf, out, cD);
}

// Round 2
// 1055.608 us; speedup vs baseline: 1.0216x; 1.0032x over previous
//
#include <hip/hip_runtime.h>

// Dims (fixed for this problem instance; start_pos read from device)
#define BATCH 32
#define DMODEL 4096
#define NH 32
#define NKV 8
#define DH 128
#define TCACHE 4096
#define NCOLS_QKV 6144   // 4096 q + 1024 k + 1024 v

// ---------------------------------------------------------------------------
// Kernel 1: QKV projection, split-K partials.
// grid (24, nchunk), block 256. Each block: 256 cols x 32 batches x dchunk K.
// ---------------------------------------------------------------------------
__global__ __launch_bounds__(256) void qkv_partial(
    const float* __restrict__ x, const float* __restrict__ wq,
    const float* __restrict__ wk, const float* __restrict__ wv,
    float* __restrict__ pbuf, int dchunk) {
  __shared__ float xs[BATCH * 128];
  const int tid = threadIdx.x, tx = tid & 63, ty = tid >> 6;
  const int bx = blockIdx.x, by = blockIdx.y;

  const float* W;
  int ldw, colw, colp;
  if (bx < 16)      { W = wq; ldw = 4096; colw = bx * 256 + tx * 4;        colp = colw; }
  else if (bx < 20) { W = wk; ldw = 1024; colw = (bx - 16) * 256 + tx * 4; colp = 4096 + colw; }
  else              { W = wv; ldw = 1024; colw = (bx - 20) * 256 + tx * 4; colp = 5120 + colw; }

  float4 acc[8];
#pragma unroll
  for (int i = 0; i < 8; ++i) acc[i] = make_float4(0.f, 0.f, 0.f, 0.f);

  const int d0 = by * dchunk;
  for (int s = 0; s < dchunk; s += 128) {
    __syncthreads();
    for (int i = tid; i < BATCH * 128; i += 256)
      xs[i] = x[(size_t)(i >> 7) * DMODEL + d0 + s + (i & 127)];
    __syncthreads();

    const float* wrow = W + (size_t)(d0 + s) * ldw + colw;
#pragma unroll 4
    for (int dd = 0; dd < 128; ++dd) {
      float4 w4 = *(const float4*)wrow;
      wrow += ldw;
#pragma unroll
      for (int i = 0; i < 8; ++i) {
        float xv = xs[(ty * 8 + i) * 128 + dd];
        acc[i].x += xv * w4.x; acc[i].y += xv * w4.y;
        acc[i].z += xv * w4.z; acc[i].w += xv * w4.w;
      }
    }
  }
#pragma unroll
  for (int i = 0; i < 8; ++i) {
    int b = ty * 8 + i;
    *(float4*)&pbuf[((size_t)by * BATCH + b) * NCOLS_QKV + colp] = acc[i];
  }
}

// ---------------------------------------------------------------------------
// Kernel 2: sum split-K partials + apply rotation.
// ---------------------------------------------------------------------------
__global__ __launch_bounds__(128) void rot_combine(
    const float* __restrict__ pbuf, const float* __restrict__ rot,
    float* __restrict__ q_ws, float* __restrict__ k_ws, float* __restrict__ v_ws,
    int nc) {
  __shared__ float xvec[DH];
  const int slot = blockIdx.x, b = blockIdx.y, e = threadIdx.x;

  int colbase;
  if (slot < 32)      colbase = slot * DH;
  else if (slot < 40) colbase = 4096 + (slot - 32) * DH;
  else                colbase = 5120 + (slot - 40) * DH;

  float s = 0.f;
  for (int c = 0; c < nc; ++c)
    s += pbuf[((size_t)c * BATCH + b) * NCOLS_QKV + colbase + e];

  if (slot >= 40) {  // v: no rotation
    v_ws[(b * NKV + slot - 40) * DH + e] = s;
    return;
  }
  xvec[e] = s;
  __syncthreads();

  const float* rb = rot + (size_t)b * DH * DH + e;
  float o = 0.f;
#pragma unroll 8
  for (int d = 0; d < DH; ++d) o += xvec[d] * rb[(size_t)d * DH];

  if (slot < 32) q_ws[(b * NH + slot) * DH + e] = o;
  else           k_ws[(b * NKV + slot - 32) * DH + e] = o;
}

// ---------------------------------------------------------------------------
// Kernel 3: attention decode. grid (NKV, BATCH), block 1024 (16 waves).
// Score phase: 16-lane groups own one K row -> fully coalesced loads, Q held
// in per-lane registers (no LDS in the hot loop), no mask loads (mask == 0
// for t <= sp; t > sp rows are exactly-zero probs and skipped).
// ---------------------------------------------------------------------------
__device__ __forceinline__ void dot128(const float* __restrict__ krp,
                                       const float* __restrict__ qhp,
                                       float& a0, float& a1, float& a2, float& a3) {
  const float4* kr = (const float4*)krp;
  const float4* q4 = (const float4*)qhp;
  a0 = a1 = a2 = a3 = 0.f;
#pragma unroll 8
  for (int c = 0; c < 32; ++c) {
    float4 kk = kr[c];
    float4 qa = q4[c], qb = q4[32 + c], qc = q4[64 + c], qd = q4[96 + c];
    a0 += kk.x * qa.x + kk.y * qa.y + kk.z * qa.z + kk.w * qa.w;
    a1 += kk.x * qb.x + kk.y * qb.y + kk.z * qb.z + kk.w * qb.w;
    a2 += kk.x * qc.x + kk.y * qc.y + kk.z * qc.z + kk.w * qc.w;
    a3 += kk.x * qd.x + kk.y * qd.y + kk.z * qd.z + kk.w * qd.w;
  }
}

__global__ __launch_bounds__(1024) void attn_kernel(
    const float* __restrict__ q_ws, const float* __restrict__ k_ws,
    const float* __restrict__ v_ws, const float* __restrict__ keys,
    const float* __restrict__ values,
    const int* __restrict__ sp_ptr, float* __restrict__ out_ws) {
  __shared__ float sc[4 * TCACHE];   // 64 KB scores/probs
  __shared__ float qh[4 * DH];
  __shared__ float kn[DH], vn[DH];
  __shared__ float red[64];          // 16 waves x 4 heads
  __shared__ float mg[4], il[4];
  __shared__ float op[16 * 4 * DH];  // 32 KB per-wave PV partials

  const int kv = blockIdx.x, b = blockIdx.y, tid = threadIdx.x;
  const int lane = tid & 63, w = tid >> 6;   // w in 0..15
  const int l16 = lane & 15, g = lane >> 4;  // 16-lane group / row-in-group
  const int sp = *sp_ptr;

  if (tid < 512)       qh[tid] = q_ws[(size_t)(b * NH + kv * 4) * DH + tid] * 0.08838834764831845f;
  else if (tid < 640)  kn[tid - 512] = k_ws[(b * NKV + kv) * DH + (tid - 512)];
  else if (tid < 768)  vn[tid - 640] = v_ws[(b * NKV + kv) * DH + (tid - 640)];
  __syncthreads();

  const size_t kvbase = (size_t)(b * NKV + kv) << 19;  // * TCACHE * DH

  // per-lane Q fragments: 4 heads x 2 chunks; chunk c covers dims (c*16+l16)*4 ..+3
  float4 qr[4][2];
#pragma unroll
  for (int h = 0; h < 4; ++h)
#pragma unroll
    for (int c = 0; c < 2; ++c)
      qr[h][c] = *(const float4*)&qh[h * DH + (c * 16 + l16) * 4];

  // ---- phase 1: scores for t in [0, sp), coalesced, fused max tracking ----
  float lm0 = -3.4e38f, lm1 = -3.4e38f, lm2 = -3.4e38f, lm3 = -3.4e38f;
  for (int tb = w * 4; tb < sp; tb += 64) {
    const int row = tb + g;
    const int rc = (row < sp) ? row : (sp - 1);   // clamp tail rows (safe load)
    const float4* kr = (const float4*)(keys + kvbase + ((size_t)rc << 7));
    float4 k0 = kr[l16];
    float4 k1 = kr[16 + l16];

    float a0 = k0.x * qr[0][0].x + k0.y * qr[0][0].y + k0.z * qr[0][0].z + k0.w * qr[0][0].w
             + k1.x * qr[0][1].x + k1.y * qr[0][1].y + k1.z * qr[0][1].z + k1.w * qr[0][1].w;
    float a1 = k0.x * qr[1][0].x + k0.y * qr[1][0].y + k0.z * qr[1][0].z + k0.w * qr[1][0].w
             + k1.x * qr[1][1].x + k1.y * qr[1][1].y + k1.z * qr[1][1].z + k1.w * qr[1][1].w;
    float a2 = k0.x * qr[2][0].x + k0.y * qr[2][0].y + k0.z * qr[2][0].z + k0.w * qr[2][0].w
             + k1.x * qr[2][1].x + k1.y * qr[2][1].y + k1.z * qr[2][1].z + k1.w * qr[2][1].w;
    float a3 = k0.x * qr[3][0].x + k0.y * qr[3][0].y + k0.z * qr[3][0].z + k0.w * qr[3][0].w
             + k1.x * qr[3][1].x + k1.y * qr[3][1].y + k1.z * qr[3][1].z + k1.w * qr[3][1].w;

#pragma unroll
    for (int off = 1; off < 16; off <<= 1) {
      a0 += __shfl_xor(a0, off, 64);
      a1 += __shfl_xor(a1, off, 64);
      a2 += __shfl_xor(a2, off, 64);
      a3 += __shfl_xor(a3, off, 64);
    }
    if (row < sp) {
      lm0 = fmaxf(lm0, a0); lm1 = fmaxf(lm1, a1);
      lm2 = fmaxf(lm2, a2); lm3 = fmaxf(lm3, a3);
      if (l16 == 0) {
        sc[row] = a0;
        sc[TCACHE + row] = a1;
        sc[2 * TCACHE + row] = a2;
        sc[3 * TCACHE + row] = a3;
      }
    }
  }
  // t == sp uses the freshly projected (rotated) k
  if (tid == (sp & 1023)) {
    float a0, a1, a2, a3;
    dot128(kn, qh, a0, a1, a2, a3);
    sc[sp] = a0;              lm0 = fmaxf(lm0, a0);
    sc[TCACHE + sp] = a1;     lm1 = fmaxf(lm1, a1);
    sc[2 * TCACHE + sp] = a2; lm2 = fmaxf(lm2, a2);
    sc[3 * TCACHE + sp] = a3; lm3 = fmaxf(lm3, a3);
  }

  // ---- softmax: max reduce (wave shuffle -> LDS -> cross-wave) ----
#pragma unroll
  for (int off = 32; off > 0; off >>= 1) {
    lm0 = fmaxf(lm0, __shfl_down(lm0, off, 64));
    lm1 = fmaxf(lm1, __shfl_down(lm1, off, 64));
    lm2 = fmaxf(lm2, __shfl_down(lm2, off, 64));
    lm3 = fmaxf(lm3, __shfl_down(lm3, off, 64));
  }
  if (lane == 0) { red[w * 4] = lm0; red[w * 4 + 1] = lm1; red[w * 4 + 2] = lm2; red[w * 4 + 3] = lm3; }
  __syncthreads();
  if (tid < 4) {
    float m = red[tid];
#pragma unroll
    for (int ww = 1; ww < 16; ++ww) m = fmaxf(m, red[ww * 4 + tid]);
    mg[tid] = m;
  }
  __syncthreads();

  // ---- softmax: exp + sum (probs written back into sc) ----
  const float m0 = mg[0], m1 = mg[1], m2 = mg[2], m3 = mg[3];
  float s0 = 0.f, s1 = 0.f, s2 = 0.f, s3 = 0.f;
  for (int t = tid; t <= sp; t += 1024) {
    float e0 = __expf(sc[t] - m0);              sc[t] = e0;              s0 += e0;
    float e1 = __expf(sc[TCACHE + t] - m1);     sc[TCACHE + t] = e1;     s1 += e1;
    float e2 = __expf(sc[2 * TCACHE + t] - m2); sc[2 * TCACHE + t] = e2; s2 += e2;
    float e3 = __expf(sc[3 * TCACHE + t] - m3); sc[3 * TCACHE + t] = e3; s3 += e3;
  }
#pragma unroll
  for (int off = 32; off > 0; off >>= 1) {
    s0 += __shfl_down(s0, off, 64);
    s1 += __shfl_down(s1, off, 64);
    s2 += __shfl_down(s2, off, 64);
    s3 += __shfl_down(s3, off, 64);
  }
  if (lane == 0) { red[w * 4] = s0; red[w * 4 + 1] = s1; red[w * 4 + 2] = s2; red[w * 4 + 3] = s3; }
  __syncthreads();
  if (tid < 4) {
    float s = 0.f;
#pragma unroll
    for (int ww = 0; ww < 16; ++ww) s += red[ww * 4 + tid];
    il[tid] = 1.0f / s;
  }
  __syncthreads();

  // ---- phase 2: PV. Each wave owns a contiguous t-chunk; coalesced V rows ----
  const int d2 = lane * 2;
  const int cnt = (sp + 16) >> 4;          // ceil((sp+1)/16)
  const int t0 = w * cnt;
  int t1 = t0 + cnt; if (t1 > sp + 1) t1 = sp + 1;
  const int tg = (t1 < sp) ? t1 : sp;      // global part: [t0, tg)

  float ox0 = 0.f, oy0 = 0.f, ox1 = 0.f, oy1 = 0.f;
  float ox2 = 0.f, oy2 = 0.f, ox3 = 0.f, oy3 = 0.f;
#pragma unroll 4
  for (int t = t0; t < tg; ++t) {
    float2 vv = *(const float2*)(values + kvbase + ((size_t)t << 7) + d2);
    float p0 = sc[t], p1 = sc[TCACHE + t], p2 = sc[2 * TCACHE + t], p3 = sc[3 * TCACHE + t];
    ox0 += p0 * vv.x; oy0 += p0 * vv.y;
    ox1 += p1 * vv.x; oy1 += p1 * vv.y;
    ox2 += p2 * vv.x; oy2 += p2 * vv.y;
    ox3 += p3 * vv.x; oy3 += p3 * vv.y;
  }
  if (sp >= t0 && sp < t1) {               // new-token row from LDS
    float vx = vn[d2], vy = vn[d2 + 1];
    float p0 = sc[sp], p1 = sc[TCACHE + sp], p2 = sc[2 * TCACHE + sp], p3 = sc[3 * TCACHE + sp];
    ox0 += p0 * vx; oy0 += p0 * vy;
    ox1 += p1 * vx; oy1 += p1 * vy;
    ox2 += p2 * vx; oy2 += p2 * vy;
    ox3 += p3 * vx; oy3 += p3 * vy;
  }
  *(float2*)&op[(w * 4 + 0) * DH + d2] = make_float2(ox0, oy0);
  *(float2*)&op[(w * 4 + 1) * DH + d2] = make_float2(ox1, oy1);
  *(float2*)&op[(w * 4 + 2) * DH + d2] = make_float2(ox2, oy2);
  *(float2*)&op[(w * 4 + 3) * DH + d2] = make_float2(ox3, oy3);
  __syncthreads();

  // cross-wave reduce; thread -> (g = tid>>7, d = tid&127)
  if (tid < 512) {
    const int gg = tid >> 7, d = tid & 127;
    float r = 0.f;
#pragma unroll
    for (int ww = 0; ww < 16; ++ww) r += op[(ww * 4 + gg) * DH + d];
    out_ws[(size_t)(b * NH + kv * 4 + gg) * DH + d] = r * il[gg];
  }
}

// ---------------------------------------------------------------------------
// Kernel 4: output projection (out_ws[32][4096] @ wo[4096][4096]), split-K.
// ---------------------------------------------------------------------------
__global__ __launch_bounds__(256) void out_partial(
    const float* __restrict__ xin, const float* __restrict__ wo,
    float* __restrict__ pbuf, int dchunk) {
  __shared__ float xs[BATCH * 128];
  const int tid = threadIdx.x, tx = tid & 63, ty = tid >> 6;
  const int bx = blockIdx.x, by = blockIdx.y;
  const int col = bx * 256 + tx * 4;

  float4 acc[8];
#pragma unroll
  for (int i = 0; i < 8; ++i) acc[i] = make_float4(0.f, 0.f, 0.f, 0.f);

  const int d0 = by * dchunk;
  for (int s = 0; s < dchunk; s += 128) {
    __syncthreads();
    for (int i = tid; i < BATCH * 128; i += 256)
      xs[i] = xin[(size_t)(i >> 7) * DMODEL + d0 + s + (i & 127)];
    __syncthreads();

    const float* wrow = wo + (size_t)(d0 + s) * DMODEL + col;
#pragma unroll 4
    for (int dd = 0; dd < 128; ++dd) {
      float4 w4 = *(const float4*)wrow;
      wrow += DMODEL;
#pragma unroll
      for (int i = 0; i < 8; ++i) {
        float xv = xs[(ty * 8 + i) * 128 + dd];
        acc[i].x += xv * w4.x; acc[i].y += xv * w4.y;
        acc[i].z += xv * w4.z; acc[i].w += xv * w4.w;
      }
    }
  }
#pragma unroll
  for (int i = 0; i < 8; ++i) {
    int b = ty * 8 + i;
    *(float4*)&pbuf[((size_t)by * BATCH + b) * DMODEL + col] = acc[i];
  }
}

// ---------------------------------------------------------------------------
// Kernel 5: reduce split-K partials into d_out.
// ---------------------------------------------------------------------------
__global__ __launch_bounds__(256) void reduce_out(
    const float* __restrict__ pbuf, float* __restrict__ out, int nc) {
  const int i = blockIdx.x * 256 + threadIdx.x;  // 131072 outputs
  const int b = i >> 12, e = i & 4095;
  float s = 0.f;
  for (int c = 0; c < nc; ++c)
    s += pbuf[((size_t)c * BATCH + b) * DMODEL + e];
  out[i] = s;
}

// ---------------------------------------------------------------------------
extern "C" void kernel_launch(void* const* d_in, const int* in_sizes, int n_in,
                              void* d_out, int out_size, void* d_ws, size_t ws_size,
                              hipStream_t stream) {
  const float* x      = (const float*)d_in[0];
  const float* wq     = (const float*)d_in[1];
  const float* wk     = (const float*)d_in[2];
  const float* wv     = (const float*)d_in[3];
  const float* wo     = (const float*)d_in[4];
  const float* rot    = (const float*)d_in[5];
  const float* keys   = (const float*)d_in[7];
  const float* values = (const float*)d_in[8];
  const int*   sp     = (const int*)d_in[9];
  float* out = (float*)d_out;
  float* ws  = (float*)d_ws;

  // aux buffers: q (131072) + k (32768) + v (32768) + attn out (131072)
  const size_t AUXF = 131072 + 32768 + 32768 + 131072;
  size_t wsf = ws_size / sizeof(float);

  int cA = 32;
  while (cA > 1 && (size_t)cA * (BATCH * NCOLS_QKV) + AUXF > wsf) cA >>= 1;
  int cD = 32;
  while (cD > 1 && (size_t)cD * (BATCH * DMODEL) + AUXF > wsf) cD >>= 1;

  size_t pmax = (size_t)cA * (BATCH * NCOLS_QKV);
  if ((size_t)cD * (BATCH * DMODEL) > pmax) pmax = (size_t)cD * (BATCH * DMODEL);

  float* pbuf   = ws;
  float* q_ws   = ws + pmax;
  float* k_ws   = q_ws + 131072;
  float* v_ws   = k_ws + 32768;
  float* out_ws = v_ws + 32768;

  qkv_partial<<<dim3(24, cA), 256, 0, stream>>>(x, wq, wk, wv, pbuf, DMODEL / cA);
  rot_combine<<<dim3(48, BATCH), 128, 0, stream>>>(pbuf, rot, q_ws, k_ws, v_ws, cA);
  attn_kernel<<<dim3(NKV, BATCH), 1024, 0, stream>>>(q_ws, k_ws, v_ws, keys, values, sp, out_ws);
  out_partial<<<dim3(16, cD), 256, 0, stream>>>(out_ws, wo, pbuf, DMODEL / cD);
  reduce_out<<<dim3(512), 256, 0, stream>>>(pbuf, out, cD);
}

// Round 3
// 1054.162 us; speedup vs baseline: 1.0230x; 1.0014x over previous
//
#include <hip/hip_runtime.h>

// Dims (fixed for this problem instance; start_pos read from device)
#define BATCH 32
#define DMODEL 4096
#define NH 32
#define NKV 8
#define DH 128
#define TCACHE 4096
#define NCOLS_QKV 6144   // 4096 q + 1024 k + 1024 v

// ---------------------------------------------------------------------------
// Kernel 1: QKV projection, split-K partials.
// grid (24, nchunk), block 256. Each block: 256 cols x 32 batches x dchunk K.
// Inner loop unrolled by 4 K-rows: ds_read_b128 for x, 4 W rows in flight.
// ---------------------------------------------------------------------------
__global__ __launch_bounds__(256) void qkv_partial(
    const float* __restrict__ x, const float* __restrict__ wq,
    const float* __restrict__ wk, const float* __restrict__ wv,
    float* __restrict__ pbuf, int dchunk) {
  __shared__ float xs[BATCH * 128];
  const int tid = threadIdx.x, tx = tid & 63, ty = tid >> 6;
  const int bx = blockIdx.x, by = blockIdx.y;

  const float* W;
  int ldw, colw, colp;
  if (bx < 16)      { W = wq; ldw = 4096; colw = bx * 256 + tx * 4;        colp = colw; }
  else if (bx < 20) { W = wk; ldw = 1024; colw = (bx - 16) * 256 + tx * 4; colp = 4096 + colw; }
  else              { W = wv; ldw = 1024; colw = (bx - 20) * 256 + tx * 4; colp = 5120 + colw; }

  float4 acc[8];
#pragma unroll
  for (int i = 0; i < 8; ++i) acc[i] = make_float4(0.f, 0.f, 0.f, 0.f);

  const int d0 = by * dchunk;
  for (int s = 0; s < dchunk; s += 128) {
    __syncthreads();
    for (int i = tid; i < BATCH * 128; i += 256)
      xs[i] = x[(size_t)(i >> 7) * DMODEL + d0 + s + (i & 127)];
    __syncthreads();

    const float* wrow = W + (size_t)(d0 + s) * ldw + colw;
    for (int dd = 0; dd < 128; dd += 4) {
      float4 w0 = *(const float4*)wrow; wrow += ldw;
      float4 w1 = *(const float4*)wrow; wrow += ldw;
      float4 w2 = *(const float4*)wrow; wrow += ldw;
      float4 w3 = *(const float4*)wrow; wrow += ldw;
#pragma unroll
      for (int i = 0; i < 8; ++i) {
        float4 xv = *(const float4*)&xs[(ty * 8 + i) * 128 + dd];
        acc[i].x += xv.x * w0.x + xv.y * w1.x + xv.z * w2.x + xv.w * w3.x;
        acc[i].y += xv.x * w0.y + xv.y * w1.y + xv.z * w2.y + xv.w * w3.y;
        acc[i].z += xv.x * w0.z + xv.y * w1.z + xv.z * w2.z + xv.w * w3.z;
        acc[i].w += xv.x * w0.w + xv.y * w1.w + xv.z * w2.w + xv.w * w3.w;
      }
    }
  }
#pragma unroll
  for (int i = 0; i < 8; ++i) {
    int b = ty * 8 + i;
    *(float4*)&pbuf[((size_t)by * BATCH + b) * NCOLS_QKV + colp] = acc[i];
  }
}

// ---------------------------------------------------------------------------
// Kernel 2: sum split-K partials + apply rotation.
// RoPE rot_mat is 2x2 block-diagonal (verified against reference builder):
//   q[2i]   = c_i*x[2i] - s_i*x[2i+1]
//   q[2i+1] = s_i*x[2i] + c_i*x[2i+1]
// with c_i = rot[2i][2i], s_i = rot[2i][2i+1]; all other entries exact zeros.
// Partner element via __shfl_xor (e^1 is always in the same wave).
// ---------------------------------------------------------------------------
__global__ __launch_bounds__(128) void rot_combine(
    const float* __restrict__ pbuf, const float* __restrict__ rot,
    float* __restrict__ q_ws, float* __restrict__ k_ws, float* __restrict__ v_ws,
    int nc) {
  const int slot = blockIdx.x, b = blockIdx.y, e = threadIdx.x;

  int colbase;
  if (slot < 32)      colbase = slot * DH;
  else if (slot < 40) colbase = 4096 + (slot - 32) * DH;
  else                colbase = 5120 + (slot - 40) * DH;

  float v = 0.f;
  for (int c = 0; c < nc; ++c)
    v += pbuf[((size_t)c * BATCH + b) * NCOLS_QKV + colbase + e];

  if (slot >= 40) {  // v: no rotation
    v_ws[(b * NKV + slot - 40) * DH + e] = v;
    return;
  }

  const float p = __shfl_xor(v, 1, 64);            // partner element x[e^1]
  const float* rb = rot + (size_t)b * DH * DH;
  const float c_ = rb[(size_t)e * DH + e];          // diagonal: cos
  const float s_ = rb[(size_t)(e & ~1) * DH + (e | 1)];  // [2i][2i+1]: sin
  const float o = (e & 1) ? fmaf(s_, p, c_ * v) : fmaf(-s_, p, c_ * v);

  if (slot < 32) q_ws[(b * NH + slot) * DH + e] = o;
  else           k_ws[(b * NKV + slot - 32) * DH + e] = o;
}

// ---------------------------------------------------------------------------
// Kernel 3: attention decode. grid (NKV, BATCH), block 1024 (16 waves).
// (unchanged from previous round)
// ---------------------------------------------------------------------------
__device__ __forceinline__ void dot128(const float* __restrict__ krp,
                                       const float* __restrict__ qhp,
                                       float& a0, float& a1, float& a2, float& a3) {
  const float4* kr = (const float4*)krp;
  const float4* q4 = (const float4*)qhp;
  a0 = a1 = a2 = a3 = 0.f;
#pragma unroll 8
  for (int c = 0; c < 32; ++c) {
    float4 kk = kr[c];
    float4 qa = q4[c], qb = q4[32 + c], qc = q4[64 + c], qd = q4[96 + c];
    a0 += kk.x * qa.x + kk.y * qa.y + kk.z * qa.z + kk.w * qa.w;
    a1 += kk.x * qb.x + kk.y * qb.y + kk.z * qb.z + kk.w * qb.w;
    a2 += kk.x * qc.x + kk.y * qc.y + kk.z * qc.z + kk.w * qc.w;
    a3 += kk.x * qd.x + kk.y * qd.y + kk.z * qd.z + kk.w * qd.w;
  }
}

__global__ __launch_bounds__(1024) void attn_kernel(
    const float* __restrict__ q_ws, const float* __restrict__ k_ws,
    const float* __restrict__ v_ws, const float* __restrict__ keys,
    const float* __restrict__ values,
    const int* __restrict__ sp_ptr, float* __restrict__ out_ws) {
  __shared__ float sc[4 * TCACHE];   // 64 KB scores/probs
  __shared__ float qh[4 * DH];
  __shared__ float kn[DH], vn[DH];
  __shared__ float red[64];          // 16 waves x 4 heads
  __shared__ float mg[4], il[4];
  __shared__ float op[16 * 4 * DH];  // 32 KB per-wave PV partials

  const int kv = blockIdx.x, b = blockIdx.y, tid = threadIdx.x;
  const int lane = tid & 63, w = tid >> 6;   // w in 0..15
  const int l16 = lane & 15, g = lane >> 4;  // 16-lane group / row-in-group
  const int sp = *sp_ptr;

  if (tid < 512)       qh[tid] = q_ws[(size_t)(b * NH + kv * 4) * DH + tid] * 0.08838834764831845f;
  else if (tid < 640)  kn[tid - 512] = k_ws[(b * NKV + kv) * DH + (tid - 512)];
  else if (tid < 768)  vn[tid - 640] = v_ws[(b * NKV + kv) * DH + (tid - 640)];
  __syncthreads();

  const size_t kvbase = (size_t)(b * NKV + kv) << 19;  // * TCACHE * DH

  // per-lane Q fragments: 4 heads x 2 chunks; chunk c covers dims (c*16+l16)*4 ..+3
  float4 qr[4][2];
#pragma unroll
  for (int h = 0; h < 4; ++h)
#pragma unroll
    for (int c = 0; c < 2; ++c)
      qr[h][c] = *(const float4*)&qh[h * DH + (c * 16 + l16) * 4];

  // ---- phase 1: scores for t in [0, sp), coalesced, fused max tracking ----
  float lm0 = -3.4e38f, lm1 = -3.4e38f, lm2 = -3.4e38f, lm3 = -3.4e38f;
  for (int tb = w * 4; tb < sp; tb += 64) {
    const int row = tb + g;
    const int rc = (row < sp) ? row : (sp - 1);   // clamp tail rows (safe load)
    const float4* kr = (const float4*)(keys + kvbase + ((size_t)rc << 7));
    float4 k0 = kr[l16];
    float4 k1 = kr[16 + l16];

    float a0 = k0.x * qr[0][0].x + k0.y * qr[0][0].y + k0.z * qr[0][0].z + k0.w * qr[0][0].w
             + k1.x * qr[0][1].x + k1.y * qr[0][1].y + k1.z * qr[0][1].z + k1.w * qr[0][1].w;
    float a1 = k0.x * qr[1][0].x + k0.y * qr[1][0].y + k0.z * qr[1][0].z + k0.w * qr[1][0].w
             + k1.x * qr[1][1].x + k1.y * qr[1][1].y + k1.z * qr[1][1].z + k1.w * qr[1][1].w;
    float a2 = k0.x * qr[2][0].x + k0.y * qr[2][0].y + k0.z * qr[2][0].z + k0.w * qr[2][0].w
             + k1.x * qr[2][1].x + k1.y * qr[2][1].y + k1.z * qr[2][1].z + k1.w * qr[2][1].w;
    float a3 = k0.x * qr[3][0].x + k0.y * qr[3][0].y + k0.z * qr[3][0].z + k0.w * qr[3][0].w
             + k1.x * qr[3][1].x + k1.y * qr[3][1].y + k1.z * qr[3][1].z + k1.w * qr[3][1].w;

#pragma unroll
    for (int off = 1; off < 16; off <<= 1) {
      a0 += __shfl_xor(a0, off, 64);
      a1 += __shfl_xor(a1, off, 64);
      a2 += __shfl_xor(a2, off, 64);
      a3 += __shfl_xor(a3, off, 64);
    }
    if (row < sp) {
      lm0 = fmaxf(lm0, a0); lm1 = fmaxf(lm1, a1);
      lm2 = fmaxf(lm2, a2); lm3 = fmaxf(lm3, a3);
      if (l16 == 0) {
        sc[row] = a0;
        sc[TCACHE + row] = a1;
        sc[2 * TCACHE + row] = a2;
        sc[3 * TCACHE + row] = a3;
      }
    }
  }
  // t == sp uses the freshly projected (rotated) k
  if (tid == (sp & 1023)) {
    float a0, a1, a2, a3;
    dot128(kn, qh, a0, a1, a2, a3);
    sc[sp] = a0;              lm0 = fmaxf(lm0, a0);
    sc[TCACHE + sp] = a1;     lm1 = fmaxf(lm1, a1);
    sc[2 * TCACHE + sp] = a2; lm2 = fmaxf(lm2, a2);
    sc[3 * TCACHE + sp] = a3; lm3 = fmaxf(lm3, a3);
  }

  // ---- softmax: max reduce (wave shuffle -> LDS -> cross-wave) ----
#pragma unroll
  for (int off = 32; off > 0; off >>= 1) {
    lm0 = fmaxf(lm0, __shfl_down(lm0, off, 64));
    lm1 = fmaxf(lm1, __shfl_down(lm1, off, 64));
    lm2 = fmaxf(lm2, __shfl_down(lm2, off, 64));
    lm3 = fmaxf(lm3, __shfl_down(lm3, off, 64));
  }
  if (lane == 0) { red[w * 4] = lm0; red[w * 4 + 1] = lm1; red[w * 4 + 2] = lm2; red[w * 4 + 3] = lm3; }
  __syncthreads();
  if (tid < 4) {
    float m = red[tid];
#pragma unroll
    for (int ww = 1; ww < 16; ++ww) m = fmaxf(m, red[ww * 4 + tid]);
    mg[tid] = m;
  }
  __syncthreads();

  // ---- softmax: exp + sum (probs written back into sc) ----
  const float m0 = mg[0], m1 = mg[1], m2 = mg[2], m3 = mg[3];
  float s0 = 0.f, s1 = 0.f, s2 = 0.f, s3 = 0.f;
  for (int t = tid; t <= sp; t += 1024) {
    float e0 = __expf(sc[t] - m0);              sc[t] = e0;              s0 += e0;
    float e1 = __expf(sc[TCACHE + t] - m1);     sc[TCACHE + t] = e1;     s1 += e1;
    float e2 = __expf(sc[2 * TCACHE + t] - m2); sc[2 * TCACHE + t] = e2; s2 += e2;
    float e3 = __expf(sc[3 * TCACHE + t] - m3); sc[3 * TCACHE + t] = e3; s3 += e3;
  }
#pragma unroll
  for (int off = 32; off > 0; off >>= 1) {
    s0 += __shfl_down(s0, off, 64);
    s1 += __shfl_down(s1, off, 64);
    s2 += __shfl_down(s2, off, 64);
    s3 += __shfl_down(s3, off, 64);
  }
  if (lane == 0) { red[w * 4] = s0; red[w * 4 + 1] = s1; red[w * 4 + 2] = s2; red[w * 4 + 3] = s3; }
  __syncthreads();
  if (tid < 4) {
    float s = 0.f;
#pragma unroll
    for (int ww = 0; ww < 16; ++ww) s += red[ww * 4 + tid];
    il[tid] = 1.0f / s;
  }
  __syncthreads();

  // ---- phase 2: PV. Each wave owns a contiguous t-chunk; coalesced V rows ----
  const int d2 = lane * 2;
  const int cnt = (sp + 16) >> 4;          // ceil((sp+1)/16)
  const int t0 = w * cnt;
  int t1 = t0 + cnt; if (t1 > sp + 1) t1 = sp + 1;
  const int tg = (t1 < sp) ? t1 : sp;      // global part: [t0, tg)

  float ox0 = 0.f, oy0 = 0.f, ox1 = 0.f, oy1 = 0.f;
  float ox2 = 0.f, oy2 = 0.f, ox3 = 0.f, oy3 = 0.f;
#pragma unroll 4
  for (int t = t0; t < tg; ++t) {
    float2 vv = *(const float2*)(values + kvbase + ((size_t)t << 7) + d2);
    float p0 = sc[t], p1 = sc[TCACHE + t], p2 = sc[2 * TCACHE + t], p3 = sc[3 * TCACHE + t];
    ox0 += p0 * vv.x; oy0 += p0 * vv.y;
    ox1 += p1 * vv.x; oy1 += p1 * vv.y;
    ox2 += p2 * vv.x; oy2 += p2 * vv.y;
    ox3 += p3 * vv.x; oy3 += p3 * vv.y;
  }
  if (sp >= t0 && sp < t1) {               // new-token row from LDS
    float vx = vn[d2], vy = vn[d2 + 1];
    float p0 = sc[sp], p1 = sc[TCACHE + sp], p2 = sc[2 * TCACHE + sp], p3 = sc[3 * TCACHE + sp];
    ox0 += p0 * vx; oy0 += p0 * vy;
    ox1 += p1 * vx; oy1 += p1 * vy;
    ox2 += p2 * vx; oy2 += p2 * vy;
    ox3 += p3 * vx; oy3 += p3 * vy;
  }
  *(float2*)&op[(w * 4 + 0) * DH + d2] = make_float2(ox0, oy0);
  *(float2*)&op[(w * 4 + 1) * DH + d2] = make_float2(ox1, oy1);
  *(float2*)&op[(w * 4 + 2) * DH + d2] = make_float2(ox2, oy2);
  *(float2*)&op[(w * 4 + 3) * DH + d2] = make_float2(ox3, oy3);
  __syncthreads();

  // cross-wave reduce; thread -> (g = tid>>7, d = tid&127)
  if (tid < 512) {
    const int gg = tid >> 7, d = tid & 127;
    float r = 0.f;
#pragma unroll
    for (int ww = 0; ww < 16; ++ww) r += op[(ww * 4 + gg) * DH + d];
    out_ws[(size_t)(b * NH + kv * 4 + gg) * DH + d] = r * il[gg];
  }
}

// ---------------------------------------------------------------------------
// Kernel 4: output projection (out_ws[32][4096] @ wo[4096][4096]), split-K.
// Inner loop unrolled by 4 K-rows, float4 LDS reads.
// ---------------------------------------------------------------------------
__global__ __launch_bounds__(256) void out_partial(
    const float* __restrict__ xin, const float* __restrict__ wo,
    float* __restrict__ pbuf, int dchunk) {
  __shared__ float xs[BATCH * 128];
  const int tid = threadIdx.x, tx = tid & 63, ty = tid >> 6;
  const int bx = blockIdx.x, by = blockIdx.y;
  const int col = bx * 256 + tx * 4;

  float4 acc[8];
#pragma unroll
  for (int i = 0; i < 8; ++i) acc[i] = make_float4(0.f, 0.f, 0.f, 0.f);

  const int d0 = by * dchunk;
  for (int s = 0; s < dchunk; s += 128) {
    __syncthreads();
    for (int i = tid; i < BATCH * 128; i += 256)
      xs[i] = xin[(size_t)(i >> 7) * DMODEL + d0 + s + (i & 127)];
    __syncthreads();

    const float* wrow = wo + (size_t)(d0 + s) * DMODEL + col;
    for (int dd = 0; dd < 128; dd += 4) {
      float4 w0 = *(const float4*)wrow; wrow += DMODEL;
      float4 w1 = *(const float4*)wrow; wrow += DMODEL;
      float4 w2 = *(const float4*)wrow; wrow += DMODEL;
      float4 w3 = *(const float4*)wrow; wrow += DMODEL;
#pragma unroll
      for (int i = 0; i < 8; ++i) {
        float4 xv = *(const float4*)&xs[(ty * 8 + i) * 128 + dd];
        acc[i].x += xv.x * w0.x + xv.y * w1.x + xv.z * w2.x + xv.w * w3.x;
        acc[i].y += xv.x * w0.y + xv.y * w1.y + xv.z * w2.y + xv.w * w3.y;
        acc[i].z += xv.x * w0.z + xv.y * w1.z + xv.z * w2.z + xv.w * w3.z;
        acc[i].w += xv.x * w0.w + xv.y * w1.w + xv.z * w2.w + xv.w * w3.w;
      }
    }
  }
#pragma unroll
  for (int i = 0; i < 8; ++i) {
    int b = ty * 8 + i;
    *(float4*)&pbuf[((size_t)by * BATCH + b) * DMODEL + col] = acc[i];
  }
}

// ---------------------------------------------------------------------------
// Kernel 5: reduce split-K partials into d_out.
// ---------------------------------------------------------------------------
__global__ __launch_bounds__(256) void reduce_out(
    const float* __restrict__ pbuf, float* __restrict__ out, int nc) {
  const int i = blockIdx.x * 256 + threadIdx.x;  // 131072 outputs
  const int b = i >> 12, e = i & 4095;
  float s = 0.f;
  for (int c = 0; c < nc; ++c)
    s += pbuf[((size_t)c * BATCH + b) * DMODEL + e];
  out[i] = s;
}

// ---------------------------------------------------------------------------
extern "C" void kernel_launch(void* const* d_in, const int* in_sizes, int n_in,
                              void* d_out, int out_size, void* d_ws, size_t ws_size,
                              hipStream_t stream) {
  const float* x      = (const float*)d_in[0];
  const float* wq     = (const float*)d_in[1];
  const float* wk     = (const float*)d_in[2];
  const float* wv     = (const float*)d_in[3];
  const float* wo     = (const float*)d_in[4];
  const float* rot    = (const float*)d_in[5];
  const float* keys   = (const float*)d_in[7];
  const float* values = (const float*)d_in[8];
  const int*   sp     = (const int*)d_in[9];
  float* out = (float*)d_out;
  float* ws  = (float*)d_ws;

  // aux buffers: q (131072) + k (32768) + v (32768) + attn out (131072)
  const size_t AUXF = 131072 + 32768 + 32768 + 131072;
  size_t wsf = ws_size / sizeof(float);

  int cA = 32;
  while (cA > 1 && (size_t)cA * (BATCH * NCOLS_QKV) + AUXF > wsf) cA >>= 1;
  int cD = 32;
  while (cD > 1 && (size_t)cD * (BATCH * DMODEL) + AUXF > wsf) cD >>= 1;

  size_t pmax = (size_t)cA * (BATCH * NCOLS_QKV);
  if ((size_t)cD * (BATCH * DMODEL) > pmax) pmax = (size_t)cD * (BATCH * DMODEL);

  float* pbuf   = ws;
  float* q_ws   = ws + pmax;
  float* k_ws   = q_ws + 131072;
  float* v_ws   = k_ws + 32768;
  float* out_ws = v_ws + 32768;

  qkv_partial<<<dim3(24, cA), 256, 0, stream>>>(x, wq, wk, wv, pbuf, DMODEL / cA);
  rot_combine<<<dim3(48, BATCH), 128, 0, stream>>>(pbuf, rot, q_ws, k_ws, v_ws, cA);
  attn_kernel<<<dim3(NKV, BATCH), 1024, 0, stream>>>(q_ws, k_ws, v_ws, keys, values, sp, out_ws);
  out_partial<<<dim3(16, cD), 256, 0, stream>>>(out_ws, wo, pbuf, DMODEL / cD);
  reduce_out<<<dim3(512), 256, 0, stream>>>(pbuf, out, cD);
}